// Round 3
// baseline (99.188 us; speedup 1.0000x reference)
//
#include <hip/hip_runtime.h>
#include <math.h>

#define NN 2048
#define EE 65536
#define FF 7
#define SS 32
#define LL 16
#define BK 128   // bucket slots per node (realized max degree ~55 for Poisson(32))

__device__ __forceinline__ float sigmoidf_(float x) { return 1.f / (1.f + expf(-x)); }

// K1: state = relu(x@W_in+b_in); msg0 = relu(state@Wm0+bm0); zero cnt[].
// Block = 256 threads = 8 nodes x 32 lanes. Row broadcasts via __shfl.
__global__ void enc_msg_kernel(const float* __restrict__ x,
                               const float* __restrict__ W_in, const float* __restrict__ b_in,
                               const float* __restrict__ Wm, const float* __restrict__ bm,
                               float* __restrict__ st_out, float* __restrict__ msg_out,
                               int* __restrict__ cnt) {
    int tid = threadIdx.x;
    int n = blockIdx.x * 8 + (tid >> 5);
    int s = tid & 31;
    const float* xr = x + n * FF;
    float acc = b_in[s];
#pragma unroll
    for (int k = 0; k < FF; k++) acc += xr[k] * W_in[k * SS + s];
    float st = fmaxf(acc, 0.f);
    st_out[n * SS + s] = st;
    float m = bm[s];
#pragma unroll
    for (int k = 0; k < SS; k++) m += __shfl(st, k, 32) * Wm[k * SS + s];
    msg_out[n * SS + s] = fmaxf(m, 0.f);
    if (blockIdx.x < 8) cnt[blockIdx.x * 256 + tid] = 0;   // zero 2048 counters
}

// K2: bucket fill. One thread per edge.
__global__ void bucket_kernel(const int* __restrict__ ei, int* __restrict__ cnt,
                              int* __restrict__ bucket) {
    int e = blockIdx.x * 256 + threadIdx.x;
    int src = ei[e], dst = ei[EE + e];
    int slot = atomicAdd(&cnt[dst], 1);
    if (slot < BK) bucket[dst * BK + slot] = src;
}

// Rounds 0,1: gather agg (bucketed, no atomics) + GRU (residual) + next message.
// Block = 256 threads = 8 nodes x 32 lanes; all row broadcasts via __shfl.
__global__ void round_kernel(const int* __restrict__ cnt, const int* __restrict__ bucket,
                             const float* __restrict__ msg_in, const float* __restrict__ st_in,
                             const float* __restrict__ Wih, const float* __restrict__ Whh,
                             const float* __restrict__ bih, const float* __restrict__ bhh,
                             const float* __restrict__ Wm, const float* __restrict__ bm,
                             float* __restrict__ st_out, float* __restrict__ msg_out) {
    int tid = threadIdx.x;
    int n = blockIdx.x * 8 + (tid >> 5);
    int s = tid & 31;
    int deg = cnt[n]; if (deg > BK) deg = BK;
    const int* bk = bucket + n * BK;
    float acc = 0.f;
    for (int base = 0; base < deg; base += 32) {
        int myk = base + s;
        int bsrc = (myk < deg) ? bk[myk] : 0;
        int m = deg - base; if (m > 32) m = 32;
#pragma unroll 4
        for (int k = 0; k < m; k++) {
            int src = __shfl(bsrc, k, 32);
            acc += msg_in[src * SS + s];
        }
    }
    float h0 = st_in[n * SS + s];
    float xr = bih[s], xz = bih[SS + s], xn = bih[2 * SS + s];
    float hr = bhh[s], hz = bhh[SS + s], hn = bhh[2 * SS + s];
#pragma unroll
    for (int k = 0; k < SS; k++) {
        float av = __shfl(acc, k, 32);
        float hv = __shfl(h0, k, 32);
        const float* wi = Wih + k * 3 * SS;
        const float* wh = Whh + k * 3 * SS;
        xr += av * wi[s];
        xz += av * wi[SS + s];
        xn += av * wi[2 * SS + s];
        hr += hv * wh[s];
        hz += hv * wh[SS + s];
        hn += hv * wh[2 * SS + s];
    }
    float rg = sigmoidf_(xr + hr);
    float zg = sigmoidf_(xz + hz);
    float ng = tanhf(xn + rg * hn);
    float st = h0 + (1.f - zg) * ng + zg * h0;
    st_out[n * SS + s] = st;
    float mv = bm[s];
#pragma unroll
    for (int k = 0; k < SS; k++) mv += __shfl(st, k, 32) * Wm[k * SS + s];
    msg_out[n * SS + s] = fmaxf(mv, 0.f);
}

// Final round: gather + GRU + mu/logstd heads + A'(b_d1 folded)/B decoder operands.
__global__ void final_kernel(const int* __restrict__ cnt, const int* __restrict__ bucket,
                             const float* __restrict__ msg_in, const float* __restrict__ st_in,
                             const float* __restrict__ Wih, const float* __restrict__ Whh,
                             const float* __restrict__ bih, const float* __restrict__ bhh,
                             const float* __restrict__ W_mu, const float* __restrict__ b_mu,
                             const float* __restrict__ W_ls, const float* __restrict__ b_ls,
                             const float* __restrict__ W_d1, const float* __restrict__ b_d1,
                             float* __restrict__ out_mu, float* __restrict__ out_ls,
                             float* __restrict__ Abuf, float* __restrict__ Bbuf) {
    int tid = threadIdx.x;
    int n = blockIdx.x * 8 + (tid >> 5);
    int s = tid & 31;
    int deg = cnt[n]; if (deg > BK) deg = BK;
    const int* bk = bucket + n * BK;
    float acc = 0.f;
    for (int base = 0; base < deg; base += 32) {
        int myk = base + s;
        int bsrc = (myk < deg) ? bk[myk] : 0;
        int m = deg - base; if (m > 32) m = 32;
#pragma unroll 4
        for (int k = 0; k < m; k++) {
            int src = __shfl(bsrc, k, 32);
            acc += msg_in[src * SS + s];
        }
    }
    float h0 = st_in[n * SS + s];
    float xr = bih[s], xz = bih[SS + s], xn = bih[2 * SS + s];
    float hr = bhh[s], hz = bhh[SS + s], hn = bhh[2 * SS + s];
#pragma unroll
    for (int k = 0; k < SS; k++) {
        float av = __shfl(acc, k, 32);
        float hv = __shfl(h0, k, 32);
        const float* wi = Wih + k * 3 * SS;
        const float* wh = Whh + k * 3 * SS;
        xr += av * wi[s];
        xz += av * wi[SS + s];
        xn += av * wi[2 * SS + s];
        hr += hv * wh[s];
        hz += hv * wh[SS + s];
        hn += hv * wh[2 * SS + s];
    }
    float rg = sigmoidf_(xr + hr);
    float zg = sigmoidf_(xz + hz);
    float ng = tanhf(xn + rg * hn);
    float st = h0 + (1.f - zg) * ng + zg * h0;
    // heads: lanes 0-15 -> mu, 16-31 -> logstd (dot over the st row via shfl)
    int l = s & 15;
    const float* W = (s < 16) ? W_mu : W_ls;
    float v = (s < 16) ? b_mu[l] : b_ls[l];
#pragma unroll
    for (int k = 0; k < SS; k++) v += __shfl(st, k, 32) * W[k * LL + l];
    if (s < 16) out_mu[n * LL + l] = v; else out_ls[n * LL + l] = v;
    // A' = mu@W_d1[:L]+b_d1 (lanes 0-15), B = mu@W_d1[L:] (lanes 16-31);
    // mu row lives in lanes 0..15 -> shfl k<16 is valid for all lanes.
    const float* Wd = W_d1 + ((s < 16) ? 0 : LL * LL);
    float ab = (s < 16) ? b_d1[l] : 0.f;
#pragma unroll
    for (int k = 0; k < LL; k++) ab += __shfl(v, k, 32) * Wd[k * LL + l];
    if (s < 16) Abuf[n * LL + l] = ab; else Bbuf[n * LL + l] = ab;
}

// Triangular-tiled decoder: block handles 64x64 (bi,bj) tile with bi<=bj,
// computes symmetric prob once per unordered pair, writes tile + transpose.
__global__ __launch_bounds__(256) void dec_kernel(const float* __restrict__ Abuf,
                                                  const float* __restrict__ Bbuf,
                                                  const float* __restrict__ W_d2,
                                                  const float* __restrict__ b_d2,
                                                  float* __restrict__ out) {
    __shared__ float ldsAj[LL * 64];
    __shared__ float ldsBj[LL * 64];
    __shared__ float ldsT[64 * 65];
    int t = blockIdx.x;
    int bi = (int)((65.f - sqrtf(4225.f - 8.f * (float)t)) * 0.5f);
    if (bi < 0) bi = 0;
    if (bi > 31) bi = 31;
    while (bi > 0 && (65 * bi - bi * bi) / 2 > t) bi--;
    while (bi < 31 && (65 * (bi + 1) - (bi + 1) * (bi + 1)) / 2 <= t) bi++;
    int bj = bi + (t - (65 * bi - bi * bi) / 2);
    int i0 = bi * 64, j0 = bj * 64;
    int tid = threadIdx.x;

    {   // stage j-side rows transposed into LDS (coalesced global float4 loads)
        int jr = tid >> 2, q = tid & 3;
        float4 va = ((const float4*)(Abuf + (size_t)(j0 + jr) * LL))[q];
        float4 vb = ((const float4*)(Bbuf + (size_t)(j0 + jr) * LL))[q];
        int l4 = q * 4;
        ldsAj[(l4 + 0) * 64 + jr] = va.x; ldsAj[(l4 + 1) * 64 + jr] = va.y;
        ldsAj[(l4 + 2) * 64 + jr] = va.z; ldsAj[(l4 + 3) * 64 + jr] = va.w;
        ldsBj[(l4 + 0) * 64 + jr] = vb.x; ldsBj[(l4 + 1) * 64 + jr] = vb.y;
        ldsBj[(l4 + 2) * 64 + jr] = vb.z; ldsBj[(l4 + 3) * 64 + jr] = vb.w;
    }
    __syncthreads();

    int jo = tid & 63;   // j lane
    int ig = tid >> 6;   // i sub-group 0..3
    float aj[LL], bjr[LL], w[LL];
#pragma unroll
    for (int l = 0; l < LL; l++) {
        aj[l] = ldsAj[l * 64 + jo];
        bjr[l] = ldsBj[l * 64 + jo];
        w[l] = W_d2[l];
    }
    float bd2 = b_d2[0];
    int j = j0 + jo;

#pragma unroll 2
    for (int ii = 0; ii < 16; ii++) {
        int i = i0 + ig * 16 + ii;
        const float4* Ai4 = (const float4*)(Abuf + (size_t)i * LL);
        const float4* Bi4 = (const float4*)(Bbuf + (size_t)i * LL);
        float4 a0 = Ai4[0], a1 = Ai4[1], a2 = Ai4[2], a3 = Ai4[3];
        float4 b0 = Bi4[0], b1 = Bi4[1], b2 = Bi4[2], b3 = Bi4[3];
        float ai[LL] = {a0.x, a0.y, a0.z, a0.w, a1.x, a1.y, a1.z, a1.w,
                        a2.x, a2.y, a2.z, a2.w, a3.x, a3.y, a3.z, a3.w};
        float bi_[LL] = {b0.x, b0.y, b0.z, b0.w, b1.x, b1.y, b1.z, b1.w,
                         b2.x, b2.y, b2.z, b2.w, b3.x, b3.y, b3.z, b3.w};
        float accij = 0.f, accji = 0.f;
#pragma unroll
        for (int l = 0; l < LL; l++) {
            accij += w[l] * fmaxf(ai[l] + bjr[l], 0.f);
            accji += w[l] * fmaxf(aj[l] + bi_[l], 0.f);
        }
        float logit = 0.5f * (accij + accji) + bd2;
        float p = 1.f / (1.f + __expf(-logit));
        out[(size_t)i * NN + j] = p;
        ldsT[jo * 65 + ig * 16 + ii] = p;
    }

    if (bi != bj) {  // transposed tile write via LDS (coalesced)
        __syncthreads();
        int jj = tid >> 2, qi = tid & 3;
        float v[16];
#pragma unroll
        for (int m = 0; m < 16; m++) v[m] = ldsT[jj * 65 + qi * 16 + m];
        float4* dst = (float4*)(out + (size_t)(j0 + jj) * NN + i0 + qi * 16);
#pragma unroll
        for (int q4 = 0; q4 < 4; q4++)
            dst[q4] = make_float4(v[4 * q4], v[4 * q4 + 1], v[4 * q4 + 2], v[4 * q4 + 3]);
    }
}

extern "C" void kernel_launch(void* const* d_in, const int* in_sizes, int n_in,
                              void* d_out, int out_size, void* d_ws, size_t ws_size,
                              hipStream_t stream) {
    const float* x    = (const float*)d_in[0];
    const int*   ei   = (const int*)d_in[1];
    const float* W_in = (const float*)d_in[2];
    const float* b_in = (const float*)d_in[3];
    const float* W_msg = (const float*)d_in[4];
    const float* b_msg = (const float*)d_in[5];
    const float* W_ih = (const float*)d_in[6];
    const float* W_hh = (const float*)d_in[7];
    const float* b_ih = (const float*)d_in[8];
    const float* b_hh = (const float*)d_in[9];
    const float* W_mu = (const float*)d_in[10];
    const float* b_mu = (const float*)d_in[11];
    const float* W_ls = (const float*)d_in[12];
    const float* b_ls = (const float*)d_in[13];
    const float* W_d1 = (const float*)d_in[14];
    const float* b_d1 = (const float*)d_in[15];
    const float* W_d2 = (const float*)d_in[16];
    const float* b_d2 = (const float*)d_in[17];

    float* ws = (float*)d_ws;
    float* stA  = ws;                   // N*S
    float* stB  = stA + NN * SS;        // N*S
    float* msgA = stB + NN * SS;        // N*S
    float* msgB = msgA + NN * SS;       // N*S
    float* Abuf = msgB + NN * SS;       // N*L
    float* Bbuf = Abuf + NN * LL;       // N*L
    int* cnt    = (int*)(Bbuf + NN * LL);   // N
    int* bucket = cnt + NN;                 // N*BK

    float* out_adj = (float*)d_out;
    float* out_mu  = out_adj + (size_t)NN * NN;
    float* out_ls  = out_mu + NN * LL;

    enc_msg_kernel<<<NN / 8, 256, 0, stream>>>(x, W_in, b_in, W_msg, b_msg,
                                               stA, msgA, cnt);
    bucket_kernel<<<EE / 256, 256, 0, stream>>>(ei, cnt, bucket);

    round_kernel<<<NN / 8, 256, 0, stream>>>(
        cnt, bucket, msgA, stA, W_ih, W_hh, b_ih, b_hh,
        W_msg + 1 * SS * SS, b_msg + 1 * SS, stB, msgB);
    round_kernel<<<NN / 8, 256, 0, stream>>>(
        cnt, bucket, msgB, stB, W_ih + SS * 3 * SS, W_hh + SS * 3 * SS,
        b_ih + 3 * SS, b_hh + 3 * SS,
        W_msg + 2 * SS * SS, b_msg + 2 * SS, stA, msgA);
    final_kernel<<<NN / 8, 256, 0, stream>>>(
        cnt, bucket, msgA, stA, W_ih + 2 * SS * 3 * SS, W_hh + 2 * SS * 3 * SS,
        b_ih + 2 * 3 * SS, b_hh + 2 * 3 * SS,
        W_mu, b_mu, W_ls, b_ls, W_d1, b_d1,
        out_mu, out_ls, Abuf, Bbuf);

    dec_kernel<<<528, 256, 0, stream>>>(Abuf, Bbuf, W_d2, b_d2, out_adj);
}

// Round 4
// 56.109 us; speedup vs baseline: 1.7678x; 1.7678x over previous
//
#include <hip/hip_runtime.h>
#include <math.h>

#define NN 2048
#define EE 65536
#define FF 7
#define SS 32
#define LL 16
#define BKT 64     // padded bucket slots per node (compile-time unrolled gather)
#define OCAP 4096  // overflow list capacity (deg > 64 edges; expected 0)

__device__ __forceinline__ float fsig(float x) { return 1.f / (1.f + __expf(-x)); }
__device__ __forceinline__ float ftanh(float x) { return 1.f - 2.f / (__expf(2.f * x) + 1.f); }

// K1: state = relu(x@W_in+b_in); msg0 = relu(state@Wm0+bm0).
// Also: zero cnt/ocnt, init bucket to pad index NN, zero msg pad rows.
// 256 blocks x 256 threads = 65536 threads = (2048 nodes x 32 lanes).
__global__ void k_enc(const float* __restrict__ x,
                      const float* __restrict__ W_in, const float* __restrict__ b_in,
                      const float* __restrict__ Wm, const float* __restrict__ bm,
                      float* __restrict__ st_out, float* __restrict__ msgA,
                      float* __restrict__ msgB,
                      int* __restrict__ cnt, int* __restrict__ ocnt,
                      int* __restrict__ bucket) {
    int gid = blockIdx.x * 256 + threadIdx.x;
    bucket[gid] = NN;                 // init all 2048*64 = 131072 slots to pad
    bucket[gid + 65536] = NN;
    if (gid < NN) cnt[gid] = 0;
    if (gid == 0) *ocnt = 0;
    if (gid < SS) { msgA[NN * SS + gid] = 0.f; msgB[NN * SS + gid] = 0.f; }

    int n = gid >> 5, s = gid & 31;
    const float* xr = x + n * FF;
    float acc = b_in[s];
#pragma unroll
    for (int k = 0; k < FF; k++) acc += xr[k] * W_in[k * SS + s];
    float st = fmaxf(acc, 0.f);
    st_out[n * SS + s] = st;
    float m = bm[s];
#pragma unroll
    for (int k = 0; k < SS; k++) m += __shfl(st, k, 32) * Wm[k * SS + s];
    msgA[n * SS + s] = fmaxf(m, 0.f);
}

// K2: bucket fill (one thread per edge); overflow past BKT goes to olist.
__global__ void k_bucket(const int* __restrict__ ei, int* __restrict__ cnt,
                         int* __restrict__ ocnt, int* __restrict__ olist,
                         int* __restrict__ bucket) {
    int e = blockIdx.x * 256 + threadIdx.x;
    int src = ei[e], dst = ei[EE + e];
    int slot = atomicAdd(&cnt[dst], 1);
    if (slot < BKT) bucket[dst * BKT + slot] = src;
    else {
        int oi = atomicAdd(ocnt, 1);
        if (oi < OCAP) { olist[2 * oi] = src; olist[2 * oi + 1] = dst; }
    }
}

// Shared: padded-64 unrolled gather + GRU(residual). Returns new state for (n,s).
__device__ __forceinline__ float gather_gru(int n, int s,
        const int* __restrict__ cnt, const int* __restrict__ bucket,
        const int* __restrict__ ocnt, const int* __restrict__ olist,
        const float* __restrict__ msg_in, const float* __restrict__ st_in,
        const float* __restrict__ Wih, const float* __restrict__ Whh,
        const float* __restrict__ bih, const float* __restrict__ bhh) {
    const int* bk = bucket + n * BKT;
    int i0 = bk[s], i1 = bk[SS + s];
    float acc = 0.f;
#pragma unroll
    for (int k = 0; k < 32; k++) acc += msg_in[__shfl(i0, k, 32) * SS + s];
#pragma unroll
    for (int k = 0; k < 32; k++) acc += msg_in[__shfl(i1, k, 32) * SS + s];
    int deg = cnt[n];
    if (deg > BKT) {                       // expected never; correctness guard
        int oc = *ocnt; if (oc > OCAP) oc = OCAP;
        for (int i = 0; i < oc; i++)
            if (olist[2 * i + 1] == n) acc += msg_in[olist[2 * i] * SS + s];
    }
    float h0 = st_in[n * SS + s];
    float xr = bih[s], xz = bih[SS + s], xn = bih[2 * SS + s];
    float hr = bhh[s], hz = bhh[SS + s], hn = bhh[2 * SS + s];
#pragma unroll
    for (int k = 0; k < SS; k++) {
        float av = __shfl(acc, k, 32);
        float hv = __shfl(h0, k, 32);
        const float* wi = Wih + k * 3 * SS;
        const float* wh = Whh + k * 3 * SS;
        xr += av * wi[s];
        xz += av * wi[SS + s];
        xn += av * wi[2 * SS + s];
        hr += hv * wh[s];
        hz += hv * wh[SS + s];
        hn += hv * wh[2 * SS + s];
    }
    float rg = fsig(xr + hr);
    float zg = fsig(xz + hz);
    float ng = ftanh(xn + rg * hn);
    return h0 + (1.f - zg) * ng + zg * h0;
}

// Rounds 0,1: gather+GRU, write new state + next message.
__global__ void k_round(const int* __restrict__ cnt, const int* __restrict__ bucket,
                        const int* __restrict__ ocnt, const int* __restrict__ olist,
                        const float* __restrict__ msg_in, const float* __restrict__ st_in,
                        const float* __restrict__ Wih, const float* __restrict__ Whh,
                        const float* __restrict__ bih, const float* __restrict__ bhh,
                        const float* __restrict__ Wm, const float* __restrict__ bm,
                        float* __restrict__ st_out, float* __restrict__ msg_out) {
    int gid = blockIdx.x * 256 + threadIdx.x;
    int n = gid >> 5, s = gid & 31;
    float st = gather_gru(n, s, cnt, bucket, ocnt, olist, msg_in, st_in,
                          Wih, Whh, bih, bhh);
    st_out[n * SS + s] = st;
    float mv = bm[s];
#pragma unroll
    for (int k = 0; k < SS; k++) mv += __shfl(st, k, 32) * Wm[k * SS + s];
    msg_out[n * SS + s] = fmaxf(mv, 0.f);
}

// Final round: gather+GRU + mu/logstd heads + A'(b_d1 folded)/B operands.
__global__ void k_final(const int* __restrict__ cnt, const int* __restrict__ bucket,
                        const int* __restrict__ ocnt, const int* __restrict__ olist,
                        const float* __restrict__ msg_in, const float* __restrict__ st_in,
                        const float* __restrict__ Wih, const float* __restrict__ Whh,
                        const float* __restrict__ bih, const float* __restrict__ bhh,
                        const float* __restrict__ W_mu, const float* __restrict__ b_mu,
                        const float* __restrict__ W_ls, const float* __restrict__ b_ls,
                        const float* __restrict__ W_d1, const float* __restrict__ b_d1,
                        float* __restrict__ out_mu, float* __restrict__ out_ls,
                        float* __restrict__ Abuf, float* __restrict__ Bbuf) {
    int gid = blockIdx.x * 256 + threadIdx.x;
    int n = gid >> 5, s = gid & 31;
    float st = gather_gru(n, s, cnt, bucket, ocnt, olist, msg_in, st_in,
                          Wih, Whh, bih, bhh);
    // heads: lanes 0-15 -> mu, 16-31 -> logstd
    int l = s & 15;
    const float* W = (s < 16) ? W_mu : W_ls;
    float v = (s < 16) ? b_mu[l] : b_ls[l];
#pragma unroll
    for (int k = 0; k < SS; k++) v += __shfl(st, k, 32) * W[k * LL + l];
    if (s < 16) out_mu[n * LL + l] = v; else out_ls[n * LL + l] = v;
    // A' = mu@W_d1[:L]+b_d1 (lanes 0-15), B = mu@W_d1[L:] (lanes 16-31);
    // mu row lives in lanes 0..15 so shfl k<16 is valid for all lanes.
    const float* Wd = W_d1 + ((s < 16) ? 0 : LL * LL);
    float ab = (s < 16) ? b_d1[l] : 0.f;
#pragma unroll
    for (int k = 0; k < LL; k++) ab += __shfl(v, k, 32) * Wd[k * LL + l];
    if (s < 16) Abuf[n * LL + l] = ab; else Bbuf[n * LL + l] = ab;
}

// Triangular-tiled decoder: 64x64 (bi,bj) tile with bi<=bj, computes symmetric
// prob once per unordered pair, writes tile + transpose (via LDS, coalesced).
__global__ __launch_bounds__(256) void dec_kernel(const float* __restrict__ Abuf,
                                                  const float* __restrict__ Bbuf,
                                                  const float* __restrict__ W_d2,
                                                  const float* __restrict__ b_d2,
                                                  float* __restrict__ out) {
    __shared__ float ldsAj[LL * 64];
    __shared__ float ldsBj[LL * 64];
    __shared__ float ldsT[64 * 65];
    int t = blockIdx.x;
    int bi = (int)((65.f - sqrtf(4225.f - 8.f * (float)t)) * 0.5f);
    if (bi < 0) bi = 0;
    if (bi > 31) bi = 31;
    while (bi > 0 && (65 * bi - bi * bi) / 2 > t) bi--;
    while (bi < 31 && (65 * (bi + 1) - (bi + 1) * (bi + 1)) / 2 <= t) bi++;
    int bj = bi + (t - (65 * bi - bi * bi) / 2);
    int i0 = bi * 64, j0 = bj * 64;
    int tid = threadIdx.x;

    {   // stage j-side rows transposed into LDS (coalesced global float4 loads)
        int jr = tid >> 2, q = tid & 3;
        float4 va = ((const float4*)(Abuf + (size_t)(j0 + jr) * LL))[q];
        float4 vb = ((const float4*)(Bbuf + (size_t)(j0 + jr) * LL))[q];
        int l4 = q * 4;
        ldsAj[(l4 + 0) * 64 + jr] = va.x; ldsAj[(l4 + 1) * 64 + jr] = va.y;
        ldsAj[(l4 + 2) * 64 + jr] = va.z; ldsAj[(l4 + 3) * 64 + jr] = va.w;
        ldsBj[(l4 + 0) * 64 + jr] = vb.x; ldsBj[(l4 + 1) * 64 + jr] = vb.y;
        ldsBj[(l4 + 2) * 64 + jr] = vb.z; ldsBj[(l4 + 3) * 64 + jr] = vb.w;
    }
    __syncthreads();

    int jo = tid & 63;   // j lane
    int ig = tid >> 6;   // i sub-group 0..3
    float aj[LL], bjr[LL], w[LL];
#pragma unroll
    for (int l = 0; l < LL; l++) {
        aj[l] = ldsAj[l * 64 + jo];
        bjr[l] = ldsBj[l * 64 + jo];
        w[l] = W_d2[l];
    }
    float bd2 = b_d2[0];
    int j = j0 + jo;

#pragma unroll 2
    for (int ii = 0; ii < 16; ii++) {
        int i = i0 + ig * 16 + ii;
        const float4* Ai4 = (const float4*)(Abuf + (size_t)i * LL);
        const float4* Bi4 = (const float4*)(Bbuf + (size_t)i * LL);
        float4 a0 = Ai4[0], a1 = Ai4[1], a2 = Ai4[2], a3 = Ai4[3];
        float4 b0 = Bi4[0], b1 = Bi4[1], b2 = Bi4[2], b3 = Bi4[3];
        float ai[LL] = {a0.x, a0.y, a0.z, a0.w, a1.x, a1.y, a1.z, a1.w,
                        a2.x, a2.y, a2.z, a2.w, a3.x, a3.y, a3.z, a3.w};
        float bi_[LL] = {b0.x, b0.y, b0.z, b0.w, b1.x, b1.y, b1.z, b1.w,
                         b2.x, b2.y, b2.z, b2.w, b3.x, b3.y, b3.z, b3.w};
        float accij = 0.f, accji = 0.f;
#pragma unroll
        for (int l = 0; l < LL; l++) {
            accij += w[l] * fmaxf(ai[l] + bjr[l], 0.f);
            accji += w[l] * fmaxf(aj[l] + bi_[l], 0.f);
        }
        float logit = 0.5f * (accij + accji) + bd2;
        float p = 1.f / (1.f + __expf(-logit));
        out[(size_t)i * NN + j] = p;
        ldsT[jo * 65 + ig * 16 + ii] = p;
    }

    if (bi != bj) {  // transposed tile write via LDS (coalesced)
        __syncthreads();
        int jj = tid >> 2, qi = tid & 3;
        float v[16];
#pragma unroll
        for (int m = 0; m < 16; m++) v[m] = ldsT[jj * 65 + qi * 16 + m];
        float4* dst = (float4*)(out + (size_t)(j0 + jj) * NN + i0 + qi * 16);
#pragma unroll
        for (int q4 = 0; q4 < 4; q4++)
            dst[q4] = make_float4(v[4 * q4], v[4 * q4 + 1], v[4 * q4 + 2], v[4 * q4 + 3]);
    }
}

extern "C" void kernel_launch(void* const* d_in, const int* in_sizes, int n_in,
                              void* d_out, int out_size, void* d_ws, size_t ws_size,
                              hipStream_t stream) {
    const float* x    = (const float*)d_in[0];
    const int*   ei   = (const int*)d_in[1];
    const float* W_in = (const float*)d_in[2];
    const float* b_in = (const float*)d_in[3];
    const float* W_msg = (const float*)d_in[4];
    const float* b_msg = (const float*)d_in[5];
    const float* W_ih = (const float*)d_in[6];
    const float* W_hh = (const float*)d_in[7];
    const float* b_ih = (const float*)d_in[8];
    const float* b_hh = (const float*)d_in[9];
    const float* W_mu = (const float*)d_in[10];
    const float* b_mu = (const float*)d_in[11];
    const float* W_ls = (const float*)d_in[12];
    const float* b_ls = (const float*)d_in[13];
    const float* W_d1 = (const float*)d_in[14];
    const float* b_d1 = (const float*)d_in[15];
    const float* W_d2 = (const float*)d_in[16];
    const float* b_d2 = (const float*)d_in[17];

    float* ws = (float*)d_ws;
    float* stA  = ws;                        // N*S
    float* stB  = stA + NN * SS;             // N*S
    float* msgA = stB + NN * SS;             // (N+1)*S  (row N = zero pad)
    float* msgB = msgA + (NN + 1) * SS;      // (N+1)*S
    float* Abuf = msgB + (NN + 1) * SS;      // N*L
    float* Bbuf = Abuf + NN * LL;            // N*L
    int* cnt    = (int*)(Bbuf + NN * LL);    // N
    int* ocnt   = cnt + NN;                  // 1
    int* olist  = ocnt + 1;                  // 2*OCAP
    int* bucket = olist + 2 * OCAP;          // N*BKT

    float* out_adj = (float*)d_out;
    float* out_mu  = out_adj + (size_t)NN * NN;
    float* out_ls  = out_mu + NN * LL;

    k_enc<<<256, 256, 0, stream>>>(x, W_in, b_in, W_msg, b_msg,
                                   stA, msgA, msgB, cnt, ocnt, bucket);
    k_bucket<<<EE / 256, 256, 0, stream>>>(ei, cnt, ocnt, olist, bucket);

    k_round<<<256, 256, 0, stream>>>(
        cnt, bucket, ocnt, olist, msgA, stA, W_ih, W_hh, b_ih, b_hh,
        W_msg + 1 * SS * SS, b_msg + 1 * SS, stB, msgB);
    k_round<<<256, 256, 0, stream>>>(
        cnt, bucket, ocnt, olist, msgB, stB,
        W_ih + SS * 3 * SS, W_hh + SS * 3 * SS, b_ih + 3 * SS, b_hh + 3 * SS,
        W_msg + 2 * SS * SS, b_msg + 2 * SS, stA, msgA);
    k_final<<<256, 256, 0, stream>>>(
        cnt, bucket, ocnt, olist, msgA, stA,
        W_ih + 2 * SS * 3 * SS, W_hh + 2 * SS * 3 * SS,
        b_ih + 2 * 3 * SS, b_hh + 2 * 3 * SS,
        W_mu, b_mu, W_ls, b_ls, W_d1, b_d1,
        out_mu, out_ls, Abuf, Bbuf);

    dec_kernel<<<528, 256, 0, stream>>>(Abuf, Bbuf, W_d2, b_d2, out_adj);
}